// Round 5
// baseline (129.779 us; speedup 1.0000x reference)
//
#include <hip/hip_runtime.h>
#include <stdint.h>
#include <stddef.h>

// out[b, p*768+e] = sum_d x[b,d]*W[p,d]*GE[d,e] + bias[p]
// == per-b GEMM: OUT_b(256x768) = (diag-x-scaled W)(256x2048) @ GT^T + bias
//
// R10 vs R9: R5/R8/R9 all obey time = SUM(LDS-read, MFMA, LDS-write) cycles
// -> zero pipe overlap at any phase/block structure we invented. This round
// is a faithful port of the m201 8-phase skeleton (the only structure
// measured at 62% MfmaUtil): 8 waves (4Mx2N, wave 64x96), 4 phases/K-tile
// of 12 MFMA, each phase {ds-reads; stage; bar; lgkm0; setprio1; MFMA;
// setprio0; bar}, counted vmcnt gates from a full ledger (vmcnt(4) @P1,
// vmcnt(2) @P3, 0 only at tail). BM=256 x BN=192: grid 64x4 = 256 blocks
// = 1/CU exact fill. LDS 116KB: A [2][2kh][256][32] 64KB | B [2][192][64]
// 48KB | X 4KB. x staged to LDS at prologue (keeps vmcnt ledger clean).
//
// Ledger (tile t, staging t+1 into dn; issue order A0,A1 @P0; B0,B1 @P1;
// B2,A2 @P2; A3 @P3): gate before bar1(P1) needs t's A2,A3 -> 4 newer ->
// vmcnt(4). gate before bar1(P3) needs t+1's A0,A1,B0,B1,B2 -> 2 newer
// (A2,A3) -> vmcnt(2). Cross-wave safety: every wave gates its own vmcnt
// before the barrier; reads of staged data are issued only after that
// barrier -> all waves' slices landed.
//
// Workspace: xb 64x2048 f16 (262144 B) | Wb 256x2048 f16 (1048576 B) |
// GT 768x2048 f16 (3145728 B) = 4,456,448 B total.

#define F_GENES 2000
#define KPAD    2048
#define P_PATH  256
#define EMB     768
#define BATCH   64
#define NT      32        // K tiles of BK=64

typedef _Float16 f16x8 __attribute__((ext_vector_type(8)));
typedef float    f32x4 __attribute__((ext_vector_type(4)));

__device__ __forceinline__ unsigned short f2h(float f) {
    union { _Float16 h; unsigned short s; } v; v.h = (_Float16)f; return v.s;
}

__device__ __forceinline__ void gload16(const void* g, void* l) {
    __builtin_amdgcn_global_load_lds((const __attribute__((address_space(1))) void*)g,
                                     (__attribute__((address_space(3))) void*)l,
                                     16, 0, 0);
}

// K1: pack x (64 rows) + W (256 rows) fp32 -> fp16, K-padded to 2048 w/ zeros.
__global__ void pack_xw_kernel(const float* __restrict__ x,
                               const float* __restrict__ w,
                               unsigned short* __restrict__ xb,
                               unsigned short* __restrict__ wb) {
    int gid = blockIdx.x * 256 + threadIdx.x;
    int row = gid >> 8;
    int s   = gid & 255;
    int d0  = s * 8;
    const float* src;
    unsigned short* dst;
    if (row < BATCH) { src = x + (size_t)row * F_GENES;           dst = xb + (size_t)row * KPAD; }
    else             { src = w + (size_t)(row - BATCH) * F_GENES; dst = wb + (size_t)(row - BATCH) * KPAD; }
    uint4 ov = make_uint4(0u, 0u, 0u, 0u);
    if (s < 250) {
        float4 v0 = *(const float4*)(src + d0);
        float4 v1 = *(const float4*)(src + d0 + 4);
        unsigned short* os = (unsigned short*)&ov;
        os[0] = f2h(v0.x); os[1] = f2h(v0.y); os[2] = f2h(v0.z); os[3] = f2h(v0.w);
        os[4] = f2h(v1.x); os[5] = f2h(v1.y); os[6] = f2h(v1.z); os[7] = f2h(v1.w);
    }
    *(uint4*)(dst + d0) = ov;
}

// K2: GT[n,k] = f16(GE[k,n]), k-padded to 2048.
__global__ void transpose_ge_kernel(const float* __restrict__ ge,
                                    unsigned short* __restrict__ GT) {
    __shared__ unsigned short tile[64][40];
    int kt = blockIdx.x & 63;
    int nt = blockIdx.x >> 6;
    int k0 = kt * 32, n0 = nt * 64;
    int t  = threadIdx.x;
    int kr = t >> 4;
    int nc = (t & 15) * 4;
#pragma unroll
    for (int p = 0; p < 2; ++p) {
        int k = k0 + p * 16 + kr;
        float4 v = make_float4(0.f, 0.f, 0.f, 0.f);
        if (k < F_GENES) v = *(const float4*)(ge + (size_t)k * EMB + n0 + nc);
        int kk = p * 16 + kr;
        tile[nc + 0][kk] = f2h(v.x);
        tile[nc + 1][kk] = f2h(v.y);
        tile[nc + 2][kk] = f2h(v.z);
        tile[nc + 3][kk] = f2h(v.w);
    }
    __syncthreads();
    int n  = t >> 2;
    int kc = (t & 3) * 8;
    uint4 o;
    unsigned short* os = (unsigned short*)&o;
#pragma unroll
    for (int j = 0; j < 8; ++j) os[j] = tile[n][kc + j];
    *(uint4*)(GT + (size_t)(n0 + n) * KPAD + k0 + kc) = o;
}

// ---- GEMM: 256x192 tile, 8 waves (4Mx2N), 4-phase m201-style pipeline ----
// LDS (f16 units): A [2 dbuf][2 kh][256 row][32] @0      (32768 f16, 64 KB)
//                  B [2 dbuf][192 row][64]       @32768  (24576 f16, 48 KB)
//                  X [2048]                      @57344  ( 2048 f16,  4 KB)
#define A_OFF 0
#define B_OFF 32768
#define X_OFF 57344

#define SBAR() __builtin_amdgcn_sched_barrier(0)
#define BAR()  do { SBAR(); __builtin_amdgcn_s_barrier(); SBAR(); } while (0)
#define LGKM0() do { asm volatile("s_waitcnt lgkmcnt(0)" ::: "memory"); SBAR(); } while (0)

__global__ __launch_bounds__(512, 2)
void gemm_kernel(const _Float16* __restrict__ xb, const _Float16* __restrict__ Wb,
                 const _Float16* __restrict__ GT, const float* __restrict__ bias,
                 float* __restrict__ out) {
    __shared__ __align__(16) _Float16 smem[59392];   // 116 KB

    const int tid  = threadIdx.x;
    const int wv   = tid >> 6;        // wave 0..7
    const int l    = tid & 63;
    const int quad = l >> 4;
    const int ln   = l & 15;
    const int wm   = wv >> 1;         // 0..3 (M quarter: 64 rows)
    const int wn   = wv & 1;          // 0..1 (N half: 96 cols)

    const int ct = blockIdx.x & 3;    // 768 / 192
    const int b  = blockIdx.x >> 2;   // batch element (BM=256 = all pathways)

    // A stage: 128 rows x 64B(kh-half) per call. c: kh = c>>1, rowbase=(c&1)*128.
#define STAGE_A(d, c, kt) do {                                                  \
    int row_ = ((c) & 1) * 128 + (tid >> 2);                                    \
    gload16(Wb + (size_t)row_ * KPAD + (kt) * 64 + ((c) >> 1) * 32              \
                + (((tid & 3) ^ ((row_ >> 1) & 3)) * 8),                        \
            smem + A_OFF + ((d) * 2 + ((c) >> 1)) * 8192                        \
                + (((c) & 1) * 128 + wv * 16) * 32);                            \
} while (0)

    // B stage: 64 rows x 128B per call (c=0..2).
#define STAGE_B(d, c, kt) do {                                                  \
    int row_ = (c) * 64 + (tid >> 3);                                           \
    gload16(GT + (size_t)(ct * 192 + row_) * KPAD + (kt) * 64                   \
                + (((tid & 7) ^ (row_ & 7)) * 8),                               \
            smem + B_OFF + (d) * 12288 + ((c) * 64 + wv * 8) * 64);             \
} while (0)

    // fragment reads (swizzle-matched; 0-conflict per R9 PMC)
#define READ_A(d, kh, mf) (*(const f16x8*)(smem + A_OFF                         \
    + ((d) * 2 + (kh)) * 8192 + (wm * 64 + (mf) * 16 + ln) * 32                 \
    + ((quad ^ ((ln >> 1) & 3)) * 8)))
#define READ_B(d, nh, nf, kh) (*(const f16x8*)(smem + B_OFF                     \
    + (d) * 12288 + (wn * 96 + (nh) * 48 + (nf) * 16 + ln) * 64                 \
    + ((((kh) * 4 + quad) ^ (ln & 7)) * 8)))
#define READ_X(kh, t) (*(const f16x8*)(smem + X_OFF + (t) * 64 + (kh) * 32 + quad * 8))

    // ---- prologue: x row -> LDS (vmcnt drained by syncthreads), then tile0 ----
    if (tid < 256) {
        f16x8 v = *(const f16x8*)(xb + (size_t)b * KPAD + tid * 8);
        *(f16x8*)(smem + X_OFF + tid * 8) = v;
    }
    __syncthreads();

    f32x4 acc[4][6];
#pragma unroll
    for (int i = 0; i < 4; ++i)
#pragma unroll
        for (int j = 0; j < 6; ++j)
            acc[i][j] = (f32x4){0.f, 0.f, 0.f, 0.f};

    // tile0 staging, ledger order: A0,A1,B0,B1,B2,A2,A3
    STAGE_A(0, 0, 0); STAGE_A(0, 1, 0);
    STAGE_B(0, 0, 0); STAGE_B(0, 1, 0); STAGE_B(0, 2, 0);
    STAGE_A(0, 2, 0); STAGE_A(0, 3, 0);
    asm volatile("s_waitcnt vmcnt(2)" ::: "memory");   // A0,A1,B0-B2 landed
    BAR();

    // ---- one K-tile: 4 phases, m201 skeleton ----
#define MFMA_CLUSTER(af, nh)                                                    \
    __builtin_amdgcn_s_setprio(1);                                              \
    _Pragma("unroll")                                                           \
    for (int nf = 0; nf < 3; ++nf)                                              \
        _Pragma("unroll")                                                       \
        for (int mf = 0; mf < 4; ++mf)                                          \
            acc[mf][(nh) * 3 + nf] = __builtin_amdgcn_mfma_f32_16x16x32_f16(    \
                af[mf], bf[nf], acc[mf][(nh) * 3 + nf], 0, 0, 0);               \
    __builtin_amdgcn_s_setprio(0);

#define DO_TILE(t, d) do {                                                      \
    const int dn_ = (d) ^ 1;                                                    \
    const bool st_ = ((t) + 1) < NT;                                            \
    f16x8 af0[4], af1[4], bf[3];                                                \
    /* P0: reads(A kh0, B kh0 nh0) | stage A0,A1(t+1) */                        \
    f16x8 xq0 = READ_X(0, (t));                                                 \
    _Pragma("unroll")                                                           \
    for (int mf = 0; mf < 4; ++mf) af0[mf] = READ_A((d), 0, mf) * xq0;          \
    _Pragma("unroll")                                                           \
    for (int nf = 0; nf < 3; ++nf) bf[nf] = READ_B((d), 0, nf, 0);              \
    if (st_) { STAGE_A(dn_, 0, (t) + 1); STAGE_A(dn_, 1, (t) + 1); }            \
    BAR(); LGKM0();                                                             \
    MFMA_CLUSTER(af0, 0);                                                       \
    BAR();                                                                      \
    /* P1: reads(B kh0 nh1) | stage B0,B1(t+1) | gate A2,A3(t) */               \
    _Pragma("unroll")                                                           \
    for (int nf = 0; nf < 3; ++nf) bf[nf] = READ_B((d), 1, nf, 0);              \
    if (st_) { STAGE_B(dn_, 0, (t) + 1); STAGE_B(dn_, 1, (t) + 1);              \
               asm volatile("s_waitcnt vmcnt(4)" ::: "memory"); }               \
    else     { asm volatile("s_waitcnt vmcnt(0)" ::: "memory"); }               \
    BAR(); LGKM0();                                                             \
    MFMA_CLUSTER(af0, 1);                                                       \
    BAR();                                                                      \
    /* P2: reads(A kh1, B kh1 nh0) | stage B2,A2(t+1) */                        \
    f16x8 xq1 = READ_X(1, (t));                                                 \
    _Pragma("unroll")                                                           \
    for (int mf = 0; mf < 4; ++mf) af1[mf] = READ_A((d), 1, mf) * xq1;          \
    _Pragma("unroll")                                                           \
    for (int nf = 0; nf < 3; ++nf) bf[nf] = READ_B((d), 0, nf, 1);              \
    if (st_) { STAGE_B(dn_, 2, (t) + 1); STAGE_A(dn_, 2, (t) + 1); }            \
    BAR(); LGKM0();                                                             \
    MFMA_CLUSTER(af1, 0);                                                       \
    BAR();                                                                      \
    /* P3: reads(B kh1 nh1) | stage A3(t+1) | gate next tile's A0A1B0-B2 */     \
    _Pragma("unroll")                                                           \
    for (int nf = 0; nf < 3; ++nf) bf[nf] = READ_B((d), 1, nf, 1);              \
    if (st_) { STAGE_A(dn_, 3, (t) + 1);                                        \
               asm volatile("s_waitcnt vmcnt(2)" ::: "memory"); }               \
    BAR(); LGKM0();                                                             \
    MFMA_CLUSTER(af1, 1);                                                       \
    BAR();                                                                      \
} while (0)

    for (int it = 0; it < NT / 2; ++it) {
        DO_TILE(2 * it,     0);
        DO_TILE(2 * it + 1, 1);
    }

    // ---- epilogue: C/D layout col=ln, row=quad*4+reg (m89/m91-verified) ----
    const size_t obase = (size_t)b * P_PATH * EMB;
#pragma unroll
    for (int mf = 0; mf < 4; ++mf) {
#pragma unroll
        for (int reg = 0; reg < 4; ++reg) {
            int p = wm * 64 + mf * 16 + quad * 4 + reg;
            float bv = bias[p];
            size_t ro = obase + (size_t)p * EMB + ct * 192 + wn * 96 + ln;
#pragma unroll
            for (int nc = 0; nc < 6; ++nc)
                out[ro + nc * 16] = acc[mf][nc][reg] + bv;
        }
    }
}

extern "C" void kernel_launch(void* const* d_in, const int* in_sizes, int n_in,
                              void* d_out, int out_size, void* d_ws, size_t ws_size,
                              hipStream_t stream) {
    // inputs (fp32): x(64x2000), weight(256x2000), bias(256), mask(unused), ge(2000x768)
    const float* x    = (const float*)d_in[0];
    const float* wgt  = (const float*)d_in[1];
    const float* bias = (const float*)d_in[2];
    const float* ge   = (const float*)d_in[4];
    float* out = (float*)d_out;

    char* ws = (char*)d_ws;
    unsigned short* xbuf = (unsigned short*)ws;                        // 262144 B
    unsigned short* Wbuf = (unsigned short*)(ws + 262144);             // 1048576 B
    unsigned short* GTb  = (unsigned short*)(ws + 262144 + 1048576);   // 3145728 B

    pack_xw_kernel<<<((BATCH + P_PATH) * 256) / 256, 256, 0, stream>>>(x, wgt, xbuf, Wbuf);
    transpose_ge_kernel<<<64 * 12, 256, 0, stream>>>(ge, GTb);
    gemm_kernel<<<dim3(BATCH * 4), dim3(512), 0, stream>>>(
        (const _Float16*)xbuf, (const _Float16*)Wbuf, (const _Float16*)GTb, bias, out);
}